// Round 14
// baseline (317.994 us; speedup 1.0000x reference)
//
#include <hip/hip_runtime.h>

#define NN 10000
#define NE 320000
#define F  128
#define CAP 96   // bucket capacity; deg = 1+Binom(310000,1e-4), P(deg>96) < 1e-20

// ---------- bf16 helpers (storage-only; all accumulation fp32) ----------
__device__ __forceinline__ float bf2f(unsigned v16) {
    return __uint_as_float(v16 << 16);
}
__device__ __forceinline__ unsigned f2bf(float f) {           // round-to-nearest-even
    unsigned u = __float_as_uint(f);
    return (u + 0x7FFFu + ((u >> 16) & 1u)) >> 16;
}
__device__ __forceinline__ unsigned pack2(float lo, float hi) {
    return f2bf(lo) | (f2bf(hi) << 16);
}
__device__ __forceinline__ void unpack8(uint4 q, float* v) {
    v[0] = bf2f(q.x & 0xffffu); v[1] = bf2f(q.x >> 16);
    v[2] = bf2f(q.y & 0xffffu); v[3] = bf2f(q.y >> 16);
    v[4] = bf2f(q.z & 0xffffu); v[5] = bf2f(q.z >> 16);
    v[6] = bf2f(q.w & 0xffffu); v[7] = bf2f(q.w >> 16);
}

// ---------- bucket-CSR build: ONE pass over edges ----------
__global__ void bucket_fill(const int* __restrict__ dst, const int* __restrict__ src,
                            int* __restrict__ cnt, int* __restrict__ buck,
                            int* __restrict__ bucksrc) {
    int e = blockIdx.x * 256 + threadIdx.x;
    if (e < NE) {
        int d = dst[e];
        int p = atomicAdd(&cnt[d], 1);
        buck[d * CAP + p]    = e;
        bucksrc[d * CAP + p] = src[e];
    }
}

// ---------- layer-1 seg-mean: fp32 edge_feats -> bf16 m ----------
// wave-per-node: lane = 2 slots x 32 float4-chunks; 8 rows in flight (stride 2)
__global__ __launch_bounds__(256) void seg_mean_k(const float4* __restrict__ ef,
                                                  const int* __restrict__ buck,
                                                  const int* __restrict__ cnt,
                                                  ushort4* __restrict__ Out) {
    int t    = threadIdx.x;
    int lane = t & 63;
    int ch   = lane & 31;       // float4 chunk
    int slot = lane >> 5;       // 0..1
    int n    = blockIdx.x * 4 + (t >> 6);
    int a = n * CAP, bnd = a + cnt[n];

    float ax = 0.f, ay = 0.f, az = 0.f, aw = 0.f;
    int i = a + slot;
    for (; i + 14 < bnd; i += 16) {       // 8 rows in flight per lane
        int s0 = buck[i],      s1 = buck[i + 2],  s2 = buck[i + 4],  s3 = buck[i + 6];
        int s4 = buck[i + 8],  s5 = buck[i + 10], s6 = buck[i + 12], s7 = buck[i + 14];
        float4 v0 = ef[(size_t)s0 * 32 + ch];
        float4 v1 = ef[(size_t)s1 * 32 + ch];
        float4 v2 = ef[(size_t)s2 * 32 + ch];
        float4 v3 = ef[(size_t)s3 * 32 + ch];
        float4 v4 = ef[(size_t)s4 * 32 + ch];
        float4 v5 = ef[(size_t)s5 * 32 + ch];
        float4 v6 = ef[(size_t)s6 * 32 + ch];
        float4 v7 = ef[(size_t)s7 * 32 + ch];
        ax += v0.x + v1.x + v2.x + v3.x + v4.x + v5.x + v6.x + v7.x;
        ay += v0.y + v1.y + v2.y + v3.y + v4.y + v5.y + v6.y + v7.y;
        az += v0.z + v1.z + v2.z + v3.z + v4.z + v5.z + v6.z + v7.z;
        aw += v0.w + v1.w + v2.w + v3.w + v4.w + v5.w + v6.w + v7.w;
    }
    for (; i < bnd; i += 2) {
        float4 v0 = ef[(size_t)buck[i] * 32 + ch];
        ax += v0.x; ay += v0.y; az += v0.z; aw += v0.w;
    }

    // reduce the 2 slots (lane bit 5); no LDS, no barrier
    ax += __shfl_xor(ax, 32, 64);
    ay += __shfl_xor(ay, 32, 64);
    az += __shfl_xor(az, 32, 64);
    aw += __shfl_xor(aw, 32, 64);

    if (slot == 0) {
        float sc = 1.0f / (float)cnt[n];
        ushort4 o;
        o.x = (unsigned short)f2bf(ax * sc);
        o.y = (unsigned short)f2bf(ay * sc);
        o.z = (unsigned short)f2bf(az * sc);
        o.w = (unsigned short)f2bf(aw * sc);
        Out[(size_t)n * 32 + ch] = o;
    }
}

// ---------- 16-deep gather core: half-wave per node (2 slots x 16 uint4-chunks) ----------
// Returns acc[8] (slot-reduced at the end by caller via shfl_xor 16).
#define GATHER16(IDX, TT, BODY)                                                         \
    int i = a + slot;                                                                   \
    for (; i + 30 < bnd; i += 32) {       /* 16 rows in flight per lane */              \
        int s0 = IDX[i],      s1 = IDX[i + 2],  s2 = IDX[i + 4],  s3 = IDX[i + 6];      \
        int s4 = IDX[i + 8],  s5 = IDX[i + 10], s6 = IDX[i + 12], s7 = IDX[i + 14];     \
        int s8 = IDX[i + 16], s9 = IDX[i + 18], sA = IDX[i + 20], sB = IDX[i + 22];     \
        int sC = IDX[i + 24], sD = IDX[i + 26], sE = IDX[i + 28], sF = IDX[i + 30];     \
        uint4 q0 = TT[(size_t)s0 * 16 + ch], q1 = TT[(size_t)s1 * 16 + ch];             \
        uint4 q2 = TT[(size_t)s2 * 16 + ch], q3 = TT[(size_t)s3 * 16 + ch];             \
        uint4 q4 = TT[(size_t)s4 * 16 + ch], q5 = TT[(size_t)s5 * 16 + ch];             \
        uint4 q6 = TT[(size_t)s6 * 16 + ch], q7 = TT[(size_t)s7 * 16 + ch];             \
        uint4 q8 = TT[(size_t)s8 * 16 + ch], q9 = TT[(size_t)s9 * 16 + ch];             \
        uint4 qA = TT[(size_t)sA * 16 + ch], qB = TT[(size_t)sB * 16 + ch];             \
        uint4 qC = TT[(size_t)sC * 16 + ch], qD = TT[(size_t)sD * 16 + ch];             \
        uint4 qE = TT[(size_t)sE * 16 + ch], qF = TT[(size_t)sF * 16 + ch];             \
        float v[8];                                                                     \
        unpack8(q0, v); BODY; unpack8(q1, v); BODY; unpack8(q2, v); BODY;               \
        unpack8(q3, v); BODY; unpack8(q4, v); BODY; unpack8(q5, v); BODY;               \
        unpack8(q6, v); BODY; unpack8(q7, v); BODY; unpack8(q8, v); BODY;               \
        unpack8(q9, v); BODY; unpack8(qA, v); BODY; unpack8(qB, v); BODY;               \
        unpack8(qC, v); BODY; unpack8(qD, v); BODY; unpack8(qE, v); BODY;               \
        unpack8(qF, v); BODY;                                                           \
    }                                                                                   \
    for (; i < bnd; i += 2) {                                                           \
        uint4 q = TT[(size_t)IDX[i] * 16 + ch];                                         \
        float v[8];                                                                     \
        unpack8(q, v); BODY;                                                            \
    }

// ---------- relu-gather (bf16 -> bf16): 128-thr block, half-wave per node, 16-deep ----
__global__ __launch_bounds__(128) void relu_gather_k(const uint4* __restrict__ T,
                                                     const int* __restrict__ bucksrc,
                                                     const int* __restrict__ cnt,
                                                     const float* __restrict__ bias,
                                                     uint4* __restrict__ Out) {
    int t    = threadIdx.x;
    int lane = t & 63;
    int ch   = lane & 15;            // uint4 chunk (8 bf16)
    int slot = (lane >> 4) & 1;      // 0..1
    int half = lane >> 5;            // node within wave
    int n    = blockIdx.x * 4 + (t >> 6) * 2 + half;
    int a = n * CAP, bnd = a + cnt[n];

    float zn[8], bb[8], acc[8];
    unpack8(T[(size_t)n * 16 + ch], zn);
#pragma unroll
    for (int j = 0; j < 8; ++j) { bb[j] = bias[ch * 8 + j]; acc[j] = 0.f; }

#define RELU_BODY { _Pragma("unroll") for (int j = 0; j < 8; ++j) \
        acc[j] += fmaxf(0.5f * (v[j] + zn[j]) + bb[j], 0.f); }
    GATHER16(bucksrc, T, RELU_BODY)
#undef RELU_BODY

#pragma unroll
    for (int j = 0; j < 8; ++j) acc[j] += __shfl_xor(acc[j], 16, 64);

    if (slot == 0) {
        float sc = 1.0f / (float)cnt[n];
        uint4 o;
        o.x = pack2(acc[0] * sc, acc[1] * sc);
        o.y = pack2(acc[2] * sc, acc[3] * sc);
        o.z = pack2(acc[4] * sc, acc[5] * sc);
        o.w = pack2(acc[6] * sc, acc[7] * sc);
        Out[(size_t)n * 16 + ch] = o;
    }
}

// ---------- sum-gather (16-deep) + fused fp32 matvec (proven 4-node shape) ----------
template <int OUT>
__global__ __launch_bounds__(128) void sum_gemm_k(const uint4* __restrict__ T,
                                                  const int* __restrict__ bucksrc,
                                                  const int* __restrict__ cnt,
                                                  const float* __restrict__ Wm,
                                                  unsigned short* __restrict__ Z) {
    __shared__ float xs[4][128];
    int t    = threadIdx.x;
    int lane = t & 63;
    int ch   = lane & 15;
    int slot = (lane >> 4) & 1;
    int half = lane >> 5;
    int nd   = (t >> 6) * 2 + half;      // node slot in block: 0..3
    int n    = blockIdx.x * 4 + nd;
    int a = n * CAP, bnd = a + cnt[n];

    float acc[8];
#pragma unroll
    for (int j = 0; j < 8; ++j) acc[j] = 0.f;

#define SUM_BODY { _Pragma("unroll") for (int j = 0; j < 8; ++j) acc[j] += v[j]; }
    GATHER16(bucksrc, T, SUM_BODY)
#undef SUM_BODY

#pragma unroll
    for (int j = 0; j < 8; ++j) acc[j] += __shfl_xor(acc[j], 16, 64);
    if (slot == 0) {
#pragma unroll
        for (int j = 0; j < 8; ++j) xs[nd][ch * 8 + j] = acc[j];
    }
    __syncthreads();

    // matvec: threads 0..OUT-1, FOUR nodes per thread (W row loaded once) — proven shape
    if (t < OUT) {
        const float4* wrow = reinterpret_cast<const float4*>(&Wm[(size_t)t * 128]);
        float a0 = 0.f, a1 = 0.f, a2 = 0.f, a3 = 0.f;
#pragma unroll 8
        for (int k4 = 0; k4 < 32; ++k4) {
            float4 w  = wrow[k4];
            float4 x0 = *reinterpret_cast<const float4*>(&xs[0][k4 * 4]);
            float4 x1 = *reinterpret_cast<const float4*>(&xs[1][k4 * 4]);
            float4 x2 = *reinterpret_cast<const float4*>(&xs[2][k4 * 4]);
            float4 x3 = *reinterpret_cast<const float4*>(&xs[3][k4 * 4]);
            a0 += w.x * x0.x + w.y * x0.y + w.z * x0.z + w.w * x0.w;
            a1 += w.x * x1.x + w.y * x1.y + w.z * x1.z + w.w * x1.w;
            a2 += w.x * x2.x + w.y * x2.y + w.z * x2.z + w.w * x2.w;
            a3 += w.x * x3.x + w.y * x3.y + w.z * x3.z + w.w * x3.w;
        }
        int nb = blockIdx.x * 4;
        Z[(size_t)(nb + 0) * OUT + t] = (unsigned short)f2bf(a0);
        Z[(size_t)(nb + 1) * OUT + t] = (unsigned short)f2bf(a1);
        Z[(size_t)(nb + 2) * OUT + t] = (unsigned short)f2bf(a2);
        Z[(size_t)(nb + 3) * OUT + t] = (unsigned short)f2bf(a3);
    }
}

// ---------- final edge output: grid-stride (G11) ----------
__global__ __launch_bounds__(256) void edge_out(const uint4* __restrict__ z5,
                                                const float* __restrict__ b5,
                                                const int* __restrict__ src,
                                                const int* __restrict__ dst,
                                                float4* __restrict__ outp) {
    int gs = gridDim.x * 256;
    for (int t = blockIdx.x * 256 + threadIdx.x; t < NE * 8; t += gs) {
        int e = t >> 3, ch = t & 7;
        float va[8], vb[8];
        unpack8(z5[(size_t)src[e] * 8 + ch], va);
        unpack8(z5[(size_t)dst[e] * 8 + ch], vb);
        float4 r0, r1;
        r0.x = 0.5f * (va[0] + vb[0]) + b5[ch * 8 + 0];
        r0.y = 0.5f * (va[1] + vb[1]) + b5[ch * 8 + 1];
        r0.z = 0.5f * (va[2] + vb[2]) + b5[ch * 8 + 2];
        r0.w = 0.5f * (va[3] + vb[3]) + b5[ch * 8 + 3];
        r1.x = 0.5f * (va[4] + vb[4]) + b5[ch * 8 + 4];
        r1.y = 0.5f * (va[5] + vb[5]) + b5[ch * 8 + 5];
        r1.z = 0.5f * (va[6] + vb[6]) + b5[ch * 8 + 6];
        r1.w = 0.5f * (va[7] + vb[7]) + b5[ch * 8 + 7];
        outp[(size_t)e * 16 + ch * 2 + 0] = r0;
        outp[(size_t)e * 16 + ch * 2 + 1] = r1;
    }
}

extern "C" void kernel_launch(void* const* d_in, const int* in_sizes, int n_in,
                              void* d_out, int out_size, void* d_ws, size_t ws_size,
                              hipStream_t stream) {
    const float* ef  = (const float*)d_in[0];
    const int*   src = (const int*)d_in[1];
    const int*   dst = (const int*)d_in[2];
    const float* W1 = (const float*)d_in[3];  const float* b1 = (const float*)d_in[4];
    const float* W2 = (const float*)d_in[5];  const float* b2 = (const float*)d_in[6];
    const float* W3 = (const float*)d_in[7];  const float* b3 = (const float*)d_in[8];
    const float* W4 = (const float*)d_in[9];  const float* b4 = (const float*)d_in[10];
    const float* W5 = (const float*)d_in[11]; const float* b5 = (const float*)d_in[12];
    float* out = (float*)d_out;

    char* p = (char*)d_ws;
    auto alloc = [&](size_t bytes) {
        char* r = p;
        p += (bytes + 255) & ~(size_t)255;
        return r;
    };
    int* cnt     = (int*)alloc(NN * 4);
    int* buck    = (int*)alloc((size_t)NN * CAP * 4);
    int* bucksrc = (int*)alloc((size_t)NN * CAP * 4);
    unsigned short* m = (unsigned short*)alloc((size_t)NN * F * 2);  // bf16
    unsigned short* z = (unsigned short*)alloc((size_t)NN * F * 2);  // bf16

    // ---- bucket-CSR build ----
    hipMemsetAsync(cnt, 0, NN * 4, stream);
    bucket_fill<<<(NE + 255) / 256, 256, 0, stream>>>(dst, src, cnt, buck, bucksrc);

    const int G4 = NN / 4;                 // 2500 blocks everywhere
    const uint4* m4 = (const uint4*)m;
    const uint4* z4 = (const uint4*)z;

    // ---- layer 1 ----
    seg_mean_k<<<G4, 256, 0, stream>>>((const float4*)ef, buck, cnt, (ushort4*)m);
    sum_gemm_k<128><<<G4, 128, 0, stream>>>(m4, bucksrc, cnt, W1, z);

    // ---- layers 2..4 (prev layer's edge compute fused into the relu gather) ----
    const float* Wl[3] = {W2, W3, W4};
    const float* bl[3] = {b1, b2, b3};
    for (int L = 0; L < 3; ++L) {
        relu_gather_k<<<G4, 128, 0, stream>>>(z4, bucksrc, cnt, bl[L], (uint4*)m);
        sum_gemm_k<128><<<G4, 128, 0, stream>>>(m4, bucksrc, cnt, Wl[L], z);
    }

    // ---- layer 5 ----
    relu_gather_k<<<G4, 128, 0, stream>>>(z4, bucksrc, cnt, b4, (uint4*)m);
    sum_gemm_k<64><<<G4, 128, 0, stream>>>(m4, bucksrc, cnt, W5, z);

    // ---- final per-edge output (82 MB write) ----
    edge_out<<<4096, 256, 0, stream>>>(z4, b5, src, dst, (float4*)out);
}

// Round 15
// 285.711 us; speedup vs baseline: 1.1130x; 1.1130x over previous
//
#include <hip/hip_runtime.h>

#define NN 10000
#define NE 320000
#define F  128
#define BLK 256
#define CAP 96   // bucket capacity; deg = 1+Binom(310000,1e-4), P(deg>96) < 1e-20

// ---------- bf16 helpers (storage-only; all accumulation fp32) ----------
__device__ __forceinline__ float bf2f(unsigned v16) {
    return __uint_as_float(v16 << 16);
}
__device__ __forceinline__ unsigned f2bf(float f) {           // round-to-nearest-even
    unsigned u = __float_as_uint(f);
    return (u + 0x7FFFu + ((u >> 16) & 1u)) >> 16;
}
__device__ __forceinline__ unsigned pack2(float lo, float hi) {
    return f2bf(lo) | (f2bf(hi) << 16);
}
__device__ __forceinline__ void unpack8(uint4 q, float* v) {
    v[0] = bf2f(q.x & 0xffffu); v[1] = bf2f(q.x >> 16);
    v[2] = bf2f(q.y & 0xffffu); v[3] = bf2f(q.y >> 16);
    v[4] = bf2f(q.z & 0xffffu); v[5] = bf2f(q.z >> 16);
    v[6] = bf2f(q.w & 0xffffu); v[7] = bf2f(q.w >> 16);
}

// ---------- zero + bucket-CSR build: ONE pass over edges ----------
__global__ void zero_cnt(int* __restrict__ cnt) {
    int i = blockIdx.x * 256 + threadIdx.x;
    if (i < NN) cnt[i] = 0;
}

__global__ void bucket_fill(const int* __restrict__ dst, const int* __restrict__ src,
                            int* __restrict__ cnt, int* __restrict__ buck,
                            int* __restrict__ bucksrc) {
    int e = blockIdx.x * 256 + threadIdx.x;
    if (e < NE) {
        int d = dst[e];
        int p = atomicAdd(&cnt[d], 1);
        buck[d * CAP + p]    = e;
        bucksrc[d * CAP + p] = src[e];
    }
}

// ---------- layer-1 seg-mean: fp32 edge_feats -> bf16 m ----------
// block = 2 nodes x 4 slots x 32 float4-chunks; 8 rows in flight per thread
__global__ __launch_bounds__(256) void seg_mean_k(const float4* __restrict__ ef,
                                                  const int* __restrict__ buck,
                                                  const int* __restrict__ cnt,
                                                  ushort4* __restrict__ Out) {
    __shared__ float4 red[8][32];
    int t  = threadIdx.x;
    int ns = t >> 7, es = (t >> 5) & 3, ch = t & 31;
    int n  = blockIdx.x * 2 + ns;
    int a = n * CAP, bnd = a + cnt[n];

    float ax = 0.f, ay = 0.f, az = 0.f, aw = 0.f;
    int i = a + es;
    for (; i + 28 < bnd; i += 32) {       // 8 rows in flight
        int s0 = buck[i],      s1 = buck[i + 4],  s2 = buck[i + 8],  s3 = buck[i + 12];
        int s4 = buck[i + 16], s5 = buck[i + 20], s6 = buck[i + 24], s7 = buck[i + 28];
        float4 v0 = ef[(size_t)s0 * 32 + ch];
        float4 v1 = ef[(size_t)s1 * 32 + ch];
        float4 v2 = ef[(size_t)s2 * 32 + ch];
        float4 v3 = ef[(size_t)s3 * 32 + ch];
        float4 v4 = ef[(size_t)s4 * 32 + ch];
        float4 v5 = ef[(size_t)s5 * 32 + ch];
        float4 v6 = ef[(size_t)s6 * 32 + ch];
        float4 v7 = ef[(size_t)s7 * 32 + ch];
        ax += v0.x + v1.x + v2.x + v3.x + v4.x + v5.x + v6.x + v7.x;
        ay += v0.y + v1.y + v2.y + v3.y + v4.y + v5.y + v6.y + v7.y;
        az += v0.z + v1.z + v2.z + v3.z + v4.z + v5.z + v6.z + v7.z;
        aw += v0.w + v1.w + v2.w + v3.w + v4.w + v5.w + v6.w + v7.w;
    }
    for (; i < bnd; i += 4) {
        float4 v0 = ef[(size_t)buck[i] * 32 + ch];
        ax += v0.x; ay += v0.y; az += v0.z; aw += v0.w;
    }

    red[(t >> 5)][ch] = make_float4(ax, ay, az, aw);
    __syncthreads();
    if (t < 64) {
        int ns2 = t >> 5, c2 = t & 31;
        float4 r0 = red[ns2 * 4 + 0][c2];
        float4 r1 = red[ns2 * 4 + 1][c2];
        float4 r2 = red[ns2 * 4 + 2][c2];
        float4 r3 = red[ns2 * 4 + 3][c2];
        int n2 = blockIdx.x * 2 + ns2;
        float sc = 1.0f / (float)cnt[n2];
        ushort4 o;
        o.x = (unsigned short)f2bf((r0.x + r1.x + r2.x + r3.x) * sc);
        o.y = (unsigned short)f2bf((r0.y + r1.y + r2.y + r3.y) * sc);
        o.z = (unsigned short)f2bf((r0.z + r1.z + r2.z + r3.z) * sc);
        o.w = (unsigned short)f2bf((r0.w + r1.w + r2.w + r3.w) * sc);
        Out[(size_t)n2 * 32 + c2] = o;
    }
}

// ---------- relu-gather (bf16 -> bf16): wave-per-node, shuffle reduce, no LDS ----------
// lane = 4 slots x 16 uint4-chunks; 8 rows in flight per lane
__global__ __launch_bounds__(256) void relu_gather_k(const uint4* __restrict__ T,
                                                     const int* __restrict__ bucksrc,
                                                     const int* __restrict__ cnt,
                                                     const float* __restrict__ bias,
                                                     uint4* __restrict__ Out) {
    int t  = threadIdx.x;
    int nd = t >> 6;            // wave = node
    int lane = t & 63;
    int ch = lane & 15;         // uint4 chunk (8 bf16)
    int es = lane >> 4;         // slot 0..3
    int n  = blockIdx.x * 4 + nd;
    int a = n * CAP, bnd = a + cnt[n];

    float zn[8], bb[8], acc[8];
    unpack8(T[(size_t)n * 16 + ch], zn);
#pragma unroll
    for (int j = 0; j < 8; ++j) { bb[j] = bias[ch * 8 + j]; acc[j] = 0.f; }

    int i = a + es;
    for (; i + 28 < bnd; i += 32) {       // 8 rows in flight
        int s0 = bucksrc[i],      s1 = bucksrc[i + 4],  s2 = bucksrc[i + 8],  s3 = bucksrc[i + 12];
        int s4 = bucksrc[i + 16], s5 = bucksrc[i + 20], s6 = bucksrc[i + 24], s7 = bucksrc[i + 28];
        uint4 q0 = T[(size_t)s0 * 16 + ch];
        uint4 q1 = T[(size_t)s1 * 16 + ch];
        uint4 q2 = T[(size_t)s2 * 16 + ch];
        uint4 q3 = T[(size_t)s3 * 16 + ch];
        uint4 q4 = T[(size_t)s4 * 16 + ch];
        uint4 q5 = T[(size_t)s5 * 16 + ch];
        uint4 q6 = T[(size_t)s6 * 16 + ch];
        uint4 q7 = T[(size_t)s7 * 16 + ch];
        float v[8];
        unpack8(q0, v);
#pragma unroll
        for (int j = 0; j < 8; ++j) acc[j] += fmaxf(0.5f * (v[j] + zn[j]) + bb[j], 0.f);
        unpack8(q1, v);
#pragma unroll
        for (int j = 0; j < 8; ++j) acc[j] += fmaxf(0.5f * (v[j] + zn[j]) + bb[j], 0.f);
        unpack8(q2, v);
#pragma unroll
        for (int j = 0; j < 8; ++j) acc[j] += fmaxf(0.5f * (v[j] + zn[j]) + bb[j], 0.f);
        unpack8(q3, v);
#pragma unroll
        for (int j = 0; j < 8; ++j) acc[j] += fmaxf(0.5f * (v[j] + zn[j]) + bb[j], 0.f);
        unpack8(q4, v);
#pragma unroll
        for (int j = 0; j < 8; ++j) acc[j] += fmaxf(0.5f * (v[j] + zn[j]) + bb[j], 0.f);
        unpack8(q5, v);
#pragma unroll
        for (int j = 0; j < 8; ++j) acc[j] += fmaxf(0.5f * (v[j] + zn[j]) + bb[j], 0.f);
        unpack8(q6, v);
#pragma unroll
        for (int j = 0; j < 8; ++j) acc[j] += fmaxf(0.5f * (v[j] + zn[j]) + bb[j], 0.f);
        unpack8(q7, v);
#pragma unroll
        for (int j = 0; j < 8; ++j) acc[j] += fmaxf(0.5f * (v[j] + zn[j]) + bb[j], 0.f);
    }
    for (; i < bnd; i += 4) {
        uint4 q = T[(size_t)bucksrc[i] * 16 + ch];
        float v[8];
        unpack8(q, v);
#pragma unroll
        for (int j = 0; j < 8; ++j) acc[j] += fmaxf(0.5f * (v[j] + zn[j]) + bb[j], 0.f);
    }

    // reduce 4 slots across lanes (bits 4,5) — no LDS, no barrier
#pragma unroll
    for (int j = 0; j < 8; ++j) {
        acc[j] += __shfl_xor(acc[j], 16, 64);
        acc[j] += __shfl_xor(acc[j], 32, 64);
    }

    if (es == 0) {
        float sc = 1.0f / (float)cnt[n];
        uint4 o;
        o.x = pack2(acc[0] * sc, acc[1] * sc);
        o.y = pack2(acc[2] * sc, acc[3] * sc);
        o.z = pack2(acc[4] * sc, acc[5] * sc);
        o.w = pack2(acc[6] * sc, acc[7] * sc);
        Out[(size_t)n * 16 + ch] = o;
    }
}

// ---------- sum-gather (bf16, wave-per-node) + fused fp32 matvec (W reuse x4) ----------
template <int OUT>
__global__ __launch_bounds__(256) void sum_gemm_k(const uint4* __restrict__ T,
                                                  const int* __restrict__ bucksrc,
                                                  const int* __restrict__ cnt,
                                                  const float* __restrict__ Wm,
                                                  unsigned short* __restrict__ Z) {
    __shared__ float xs[4][128];
    int t  = threadIdx.x;
    int nd = t >> 6;
    int lane = t & 63;
    int ch = lane & 15;
    int es = lane >> 4;
    int n  = blockIdx.x * 4 + nd;
    int a = n * CAP, bnd = a + cnt[n];

    float acc[8];
#pragma unroll
    for (int j = 0; j < 8; ++j) acc[j] = 0.f;

    int i = a + es;
    for (; i + 28 < bnd; i += 32) {       // 8 rows in flight
        int s0 = bucksrc[i],      s1 = bucksrc[i + 4],  s2 = bucksrc[i + 8],  s3 = bucksrc[i + 12];
        int s4 = bucksrc[i + 16], s5 = bucksrc[i + 20], s6 = bucksrc[i + 24], s7 = bucksrc[i + 28];
        uint4 q0 = T[(size_t)s0 * 16 + ch];
        uint4 q1 = T[(size_t)s1 * 16 + ch];
        uint4 q2 = T[(size_t)s2 * 16 + ch];
        uint4 q3 = T[(size_t)s3 * 16 + ch];
        uint4 q4 = T[(size_t)s4 * 16 + ch];
        uint4 q5 = T[(size_t)s5 * 16 + ch];
        uint4 q6 = T[(size_t)s6 * 16 + ch];
        uint4 q7 = T[(size_t)s7 * 16 + ch];
        float v[8];
        unpack8(q0, v);
#pragma unroll
        for (int j = 0; j < 8; ++j) acc[j] += v[j];
        unpack8(q1, v);
#pragma unroll
        for (int j = 0; j < 8; ++j) acc[j] += v[j];
        unpack8(q2, v);
#pragma unroll
        for (int j = 0; j < 8; ++j) acc[j] += v[j];
        unpack8(q3, v);
#pragma unroll
        for (int j = 0; j < 8; ++j) acc[j] += v[j];
        unpack8(q4, v);
#pragma unroll
        for (int j = 0; j < 8; ++j) acc[j] += v[j];
        unpack8(q5, v);
#pragma unroll
        for (int j = 0; j < 8; ++j) acc[j] += v[j];
        unpack8(q6, v);
#pragma unroll
        for (int j = 0; j < 8; ++j) acc[j] += v[j];
        unpack8(q7, v);
#pragma unroll
        for (int j = 0; j < 8; ++j) acc[j] += v[j];
    }
    for (; i < bnd; i += 4) {
        uint4 q = T[(size_t)bucksrc[i] * 16 + ch];
        float v[8];
        unpack8(q, v);
#pragma unroll
        for (int j = 0; j < 8; ++j) acc[j] += v[j];
    }

#pragma unroll
    for (int j = 0; j < 8; ++j) {
        acc[j] += __shfl_xor(acc[j], 16, 64);
        acc[j] += __shfl_xor(acc[j], 32, 64);
    }
    if (es == 0) {
#pragma unroll
        for (int j = 0; j < 8; ++j) xs[nd][ch * 8 + j] = acc[j];
    }
    __syncthreads();

    // matvec: threads 0..OUT-1, FOUR nodes per thread (W row loaded once)
    if (t < OUT) {
        const float4* wrow = reinterpret_cast<const float4*>(&Wm[(size_t)t * 128]);
        float a0 = 0.f, a1 = 0.f, a2 = 0.f, a3 = 0.f;
#pragma unroll 8
        for (int k4 = 0; k4 < 32; ++k4) {
            float4 w  = wrow[k4];
            float4 x0 = *reinterpret_cast<const float4*>(&xs[0][k4 * 4]);
            float4 x1 = *reinterpret_cast<const float4*>(&xs[1][k4 * 4]);
            float4 x2 = *reinterpret_cast<const float4*>(&xs[2][k4 * 4]);
            float4 x3 = *reinterpret_cast<const float4*>(&xs[3][k4 * 4]);
            a0 += w.x * x0.x + w.y * x0.y + w.z * x0.z + w.w * x0.w;
            a1 += w.x * x1.x + w.y * x1.y + w.z * x1.z + w.w * x1.w;
            a2 += w.x * x2.x + w.y * x2.y + w.z * x2.z + w.w * x2.w;
            a3 += w.x * x3.x + w.y * x3.y + w.z * x3.z + w.w * x3.w;
        }
        int nb = blockIdx.x * 4;
        Z[(size_t)(nb + 0) * OUT + t] = (unsigned short)f2bf(a0);
        Z[(size_t)(nb + 1) * OUT + t] = (unsigned short)f2bf(a1);
        Z[(size_t)(nb + 2) * OUT + t] = (unsigned short)f2bf(a2);
        Z[(size_t)(nb + 3) * OUT + t] = (unsigned short)f2bf(a3);
    }
}

// ---------- final edge output (proven) ----------
__global__ __launch_bounds__(256) void edge_out(const uint4* __restrict__ z5,
                                                const float* __restrict__ b5,
                                                const int* __restrict__ src,
                                                const int* __restrict__ dst,
                                                float4* __restrict__ outp) {
    int t = blockIdx.x * 256 + threadIdx.x;
    int e = t >> 3, ch = t & 7;
    if (e < NE) {
        float va[8], vb[8];
        unpack8(z5[(size_t)src[e] * 8 + ch], va);
        unpack8(z5[(size_t)dst[e] * 8 + ch], vb);
        float4 r0, r1;
        r0.x = 0.5f * (va[0] + vb[0]) + b5[ch * 8 + 0];
        r0.y = 0.5f * (va[1] + vb[1]) + b5[ch * 8 + 1];
        r0.z = 0.5f * (va[2] + vb[2]) + b5[ch * 8 + 2];
        r0.w = 0.5f * (va[3] + vb[3]) + b5[ch * 8 + 3];
        r1.x = 0.5f * (va[4] + vb[4]) + b5[ch * 8 + 4];
        r1.y = 0.5f * (va[5] + vb[5]) + b5[ch * 8 + 5];
        r1.z = 0.5f * (va[6] + vb[6]) + b5[ch * 8 + 6];
        r1.w = 0.5f * (va[7] + vb[7]) + b5[ch * 8 + 7];
        outp[(size_t)e * 16 + ch * 2 + 0] = r0;
        outp[(size_t)e * 16 + ch * 2 + 1] = r1;
    }
}

extern "C" void kernel_launch(void* const* d_in, const int* in_sizes, int n_in,
                              void* d_out, int out_size, void* d_ws, size_t ws_size,
                              hipStream_t stream) {
    const float* ef  = (const float*)d_in[0];
    const int*   src = (const int*)d_in[1];
    const int*   dst = (const int*)d_in[2];
    const float* W1 = (const float*)d_in[3];  const float* b1 = (const float*)d_in[4];
    const float* W2 = (const float*)d_in[5];  const float* b2 = (const float*)d_in[6];
    const float* W3 = (const float*)d_in[7];  const float* b3 = (const float*)d_in[8];
    const float* W4 = (const float*)d_in[9];  const float* b4 = (const float*)d_in[10];
    const float* W5 = (const float*)d_in[11]; const float* b5 = (const float*)d_in[12];
    float* out = (float*)d_out;

    char* p = (char*)d_ws;
    auto alloc = [&](size_t bytes) {
        char* r = p;
        p += (bytes + 255) & ~(size_t)255;
        return r;
    };
    int* cnt     = (int*)alloc(NN * 4);
    int* buck    = (int*)alloc((size_t)NN * CAP * 4);
    int* bucksrc = (int*)alloc((size_t)NN * CAP * 4);
    unsigned short* m = (unsigned short*)alloc((size_t)NN * F * 2);  // bf16
    unsigned short* z = (unsigned short*)alloc((size_t)NN * F * 2);  // bf16

    // ---- bucket-CSR build ----
    zero_cnt<<<(NN + 255) / 256, 256, 0, stream>>>(cnt);
    bucket_fill<<<(NE + 255) / 256, 256, 0, stream>>>(dst, src, cnt, buck, bucksrc);

    const int G2 = NN / 2;                 // seg_mean: 2 nodes/block
    const int G4 = NN / 4;                 // gathers:  4 nodes/block (wave-per-node)
    const uint4* m4 = (const uint4*)m;
    const uint4* z4 = (const uint4*)z;

    // ---- layer 1 ----
    seg_mean_k<<<G2, BLK, 0, stream>>>((const float4*)ef, buck, cnt, (ushort4*)m);
    sum_gemm_k<128><<<G4, BLK, 0, stream>>>(m4, bucksrc, cnt, W1, z);

    // ---- layers 2..4 (prev layer's edge compute fused into the relu gather) ----
    const float* Wl[3] = {W2, W3, W4};
    const float* bl[3] = {b1, b2, b3};
    for (int L = 0; L < 3; ++L) {
        relu_gather_k<<<G4, BLK, 0, stream>>>(z4, bucksrc, cnt, bl[L], (uint4*)m);
        sum_gemm_k<128><<<G4, BLK, 0, stream>>>(m4, bucksrc, cnt, Wl[L], z);
    }

    // ---- layer 5 ----
    relu_gather_k<<<G4, BLK, 0, stream>>>(z4, bucksrc, cnt, b4, (uint4*)m);
    sum_gemm_k<64><<<G4, BLK, 0, stream>>>(m4, bucksrc, cnt, W5, z);

    // ---- final per-edge output (82 MB write) ----
    edge_out<<<(NE * 8 + 255) / 256, BLK, 0, stream>>>(z4, b5, src, dst, (float4*)out);
}